// Round 8
// baseline (306.068 us; speedup 1.0000x reference)
//
#include <hip/hip_runtime.h>
#include <hip/hip_bf16.h>

#define IN_DIM   8
#define IN_CAPS  1152
#define OUT_CAPS 10
#define OUT_DIM  16
#define BATCH    512
#define CSPLIT   32
#define CCHUNK   (IN_CAPS / CSPLIT)     // 36 c per block
#define NT4      (CCHUNK / 4)           // 9 tile4 per block
#define BT       16                     // batches per block (MFMA N)
#define NBT      (BATCH / BT)           // 32
#define SSZ      (BATCH * OUT_CAPS * OUT_DIM)   // 81920 f32
#define SROW     164                    // shorts per b-row in s_bf
#define ACCROW   168                    // f32 per b-row in sacc (42 float4)
#define XROW     (CCHUNK * IN_DIM + 4)  // 292 f32 per b-row in xs
#define PARTSZ   (CSPLIT * SSZ)         // 2,621,440 f32 = 10.49 MB

typedef float  f32x4 __attribute__((ext_vector_type(4)));
typedef short  s16x8 __attribute__((ext_vector_type(8)));

static __device__ __forceinline__ short f2bs(float f) {
  __hip_bfloat16 h = __float2bfloat16(f);
  short s;
  __builtin_memcpy(&s, &h, 2);
  return s;
}

// MODE 0: cw = 0.1 (softmax of zero logits)  -> part
// MODE 1: logits from sA (=s1)               -> part
// MODE 2: logits from sA+sB (=s1+s2)         -> part
// MFMA 16x16x32 frag k-map (two 16x16x16 halves):
//   elem j<4 : k = 4*(lane>>4)+j ; elem j>=4 : k = 16+4*(lane>>4)+(j-4)
//   A row m = lane&15 ; B col n = lane&15 ; D: col = lane&15, row = 4*(lane>>4)+reg
template<int MODE>
__global__ __launch_bounds__(256, 4) void sweep_kernel(
    const float* __restrict__ x, const float* __restrict__ W,
    const float* __restrict__ sA, const float* __restrict__ sB,
    float* __restrict__ part) {
  __shared__ short s_bf[16 * SROW];      // 5.2 KB  s[b][o*16+d] bf16
  __shared__ float xs[16 * XROW];        // 18.7 KB x[b][cl*8+i]
  __shared__ float sacc[16 * ACCROW];    // 10.8 KB single-copy partial

  const int tid  = threadIdx.x;
  const int wid  = tid >> 6;
  const int lane = tid & 63;
  const int b    = lane & 15;            // batch-in-tile / d / ci (role per frag)
  const int g    = lane >> 4;            // k-group
  const int bt   = blockIdx.x / CSPLIT;
  const int ch   = blockIdx.x % CSPLIT;  // xcd = ch%8 by default round-robin -> W L2 locality
  const int c0   = ch * CCHUNK;
  const int bb0  = bt * BT;

  // stage x slice (contiguous per b-row: 288 f32 = 72 float4)
  for (int idx = tid; idx < 16 * 72; idx += 256) {
    int bb = idx / 72, j = idx % 72;
    *(float4*)(xs + bb * XROW + j * 4) =
        *(const float4*)(x + ((size_t)(bb0 + bb) * IN_CAPS + c0) * IN_DIM + j * 4);
  }
  if (MODE != 0) {
    for (int k = tid; k < 16 * 160; k += 256) {
      int bb = k / 160, od = k % 160;
      float v = sA[(size_t)(bb0 + bb) * 160 + od];
      if (MODE == 2) v += sB[(size_t)(bb0 + bb) * 160 + od];
      s_bf[bb * SROW + od] = f2bs(v);
    }
  }
  for (int k = tid; k < 16 * ACCROW; k += 256) sacc[k] = 0.f;
  __syncthreads();

  f32x4 acc[OUT_CAPS];
  #pragma unroll
  for (int o = 0; o < OUT_CAPS; ++o) acc[o] = (f32x4){0.f, 0.f, 0.f, 0.f};

  const int isub = 4 * (g & 1);

  for (int t = wid; t < NT4; t += 4) {
    const int clA = t * 4 + (g >> 1);        // local c, half 0
    const int clB = clA + 2;                 // local c, half 1
    const int cA  = c0 + clA;
    const int cB  = c0 + clB;
    const float4 xq0 = *(const float4*)(xs + b * XROW + clA * IN_DIM + isub);
    const float4 xq1 = *(const float4*)(xs + b * XROW + clB * IN_DIM + isub);

    float lg[2][OUT_CAPS];

    if (MODE != 0) {
      #pragma unroll
      for (int o = 0; o < OUT_CAPS; ++o) {
        // B1 frag: s[b][o][d], k=d (j<4 real; j>=4 zero-pad)
        ushort4 sv = *(const ushort4*)&s_bf[b * SROW + o * 16 + 4 * g];
        s16x8 sb = {(short)sv.x, (short)sv.y, (short)sv.z, (short)sv.w, 0, 0, 0, 0};
        #pragma unroll
        for (int h = 0; h < 2; ++h) {
          // A1 frag: rows m -> (c = c4+2h+(m>>3), i = m&7); k=d=4g+j
          const int cm = c0 + t * 4 + 2 * h + (b >> 3);
          const float* wp = W + (((size_t)o * IN_CAPS + cm) * OUT_DIM + 4 * g) * IN_DIM + (b & 7);
          s16x8 a1 = {f2bs(wp[0]), f2bs(wp[8]), f2bs(wp[16]), f2bs(wp[24]), 0, 0, 0, 0};
          f32x4 zz = (f32x4){0.f, 0.f, 0.f, 0.f};
          f32x4 d1 = __builtin_amdgcn_mfma_f32_16x16x32_bf16(a1, sb, zz, 0, 0, 0);
          const float4 xq = h ? xq1 : xq0;
          float p = d1[0] * xq.x + d1[1] * xq.y + d1[2] * xq.z + d1[3] * xq.w;
          p += __shfl_xor(p, 16);            // pair (g, g^1) completes sum over i
          lg[h][o] = p;
        }
      }
      #pragma unroll
      for (int h = 0; h < 2; ++h) {
        float m = lg[h][0];
        #pragma unroll
        for (int o = 1; o < OUT_CAPS; ++o) m = fmaxf(m, lg[h][o]);
        float sum = 0.f;
        #pragma unroll
        for (int o = 0; o < OUT_CAPS; ++o) { lg[h][o] = __expf(lg[h][o] - m); sum += lg[h][o]; }
        float inv = 1.f / sum;
        #pragma unroll
        for (int o = 0; o < OUT_CAPS; ++o) lg[h][o] *= inv;
      }
    }

    // GEMM2: acc[o][d,b] += sum_ci W[o,ci,d] * (cw*x)[b,ci]
    #pragma unroll
    for (int o = 0; o < OUT_CAPS; ++o) {
      const float cwA = (MODE == 0) ? 0.1f : lg[0][o];
      const float cwB = (MODE == 0) ? 0.1f : lg[1][o];
      s16x8 z8 = {f2bs(cwA * xq0.x), f2bs(cwA * xq0.y), f2bs(cwA * xq0.z), f2bs(cwA * xq0.w),
                  f2bs(cwB * xq1.x), f2bs(cwB * xq1.y), f2bs(cwB * xq1.z), f2bs(cwB * xq1.w)};
      const float4 wva = *(const float4*)(W + (((size_t)o * IN_CAPS + cA) * OUT_DIM + b) * IN_DIM + isub);
      const float4 wvb = *(const float4*)(W + (((size_t)o * IN_CAPS + cB) * OUT_DIM + b) * IN_DIM + isub);
      s16x8 a2 = {f2bs(wva.x), f2bs(wva.y), f2bs(wva.z), f2bs(wva.w),
                  f2bs(wvb.x), f2bs(wvb.y), f2bs(wvb.z), f2bs(wvb.w)};
      acc[o] = __builtin_amdgcn_mfma_f32_16x16x32_bf16(a2, z8, acc[o], 0, 0, 0);
    }
  }

  // cross-wave reduce via LDS atomicAdd (each slot hit once per wave)
  {
    float* sa = &sacc[b * ACCROW];
    #pragma unroll
    for (int o = 0; o < OUT_CAPS; ++o) {
      #pragma unroll
      for (int r = 0; r < 4; ++r) atomicAdd(&sa[o * 16 + 4 * g + r], acc[o][r]);
    }
  }
  __syncthreads();

  // coalesced float4 partial store: part[ch][bb0+bb][od]
  {
    float4* dst = (float4*)(part + ((size_t)ch * BATCH + bb0) * 160);
    for (int k = tid; k < 640; k += 256) {
      int bb = k / 40, q = k % 40;
      dst[k] = *(const float4*)(sacc + bb * ACCROW + q * 4);
    }
  }
}

__global__ __launch_bounds__(256) void reduce_kernel(
    const float* __restrict__ part, float* __restrict__ dst) {
  const int i = blockIdx.x * 256 + threadIdx.x;      // float4 index, 20480 total
  const float4* p4 = (const float4*)part;
  float4 s = p4[i];
  #pragma unroll
  for (int ch = 1; ch < CSPLIT; ++ch) {
    float4 a = p4[(size_t)ch * (SSZ / 4) + i];
    s.x += a.x; s.y += a.y; s.z += a.z; s.w += a.w;
  }
  ((float4*)dst)[i] = s;
}

extern "C" void kernel_launch(void* const* d_in, const int* in_sizes, int n_in,
                              void* d_out, int out_size, void* d_ws, size_t ws_size,
                              hipStream_t stream) {
  const float* x = (const float*)d_in[0];
  const float* W = (const float*)d_in[1];
  float* out  = (float*)d_out;
  float* part = (float*)d_ws;             // CSPLIT * SSZ f32
  float* wsA  = part + PARTSZ;            // s1
  float* wsB  = wsA + SSZ;                // s2
  const int GRID = NBT * CSPLIT;          // 1024

  sweep_kernel<0><<<GRID, 256, 0, stream>>>(x, W, wsA, wsB, part);
  reduce_kernel<<<SSZ / 4 / 256, 256, 0, stream>>>(part, wsA);     // wsA = s1
  sweep_kernel<1><<<GRID, 256, 0, stream>>>(x, W, wsA, wsB, part);
  reduce_kernel<<<SSZ / 4 / 256, 256, 0, stream>>>(part, wsB);     // wsB = s2
  sweep_kernel<2><<<GRID, 256, 0, stream>>>(x, W, wsA, wsB, part);
  reduce_kernel<<<SSZ / 4 / 256, 256, 0, stream>>>(part, out);     // out = v
}